// Round 11
// baseline (198.863 us; speedup 1.0000x reference)
//
#include <hip/hip_runtime.h>
#include <hip/hip_bf16.h>

#define HH   300
#define NB   128
#define NTT  64
#define NP   8192        // B*T
#define NCH  12
#define KPAD 320         // padded K (300 -> 320)
#define NTI2 14          // 13 e-tiles + 1 g-tile (H / T column at e=208)

typedef __attribute__((ext_vector_type(8))) short short8;
typedef __attribute__((ext_vector_type(4))) float f32x4;

__device__ __forceinline__ float fsig(float x){
  return __builtin_amdgcn_rcpf(1.f + __expf(-x));
}
__device__ __forceinline__ float ftanh(float x){
  float e = __expf(2.f*x);
  return 1.f - 2.f*__builtin_amdgcn_rcpf(e + 1.f);   // safe at +/-inf
}
__device__ __forceinline__ float bf2f(unsigned short u){
  return __uint_as_float(((unsigned)u) << 16);
}
__device__ __forceinline__ unsigned short f2bf(float f){      // RNE
  __hip_bfloat16 h = __float2bfloat16(f);
  return *reinterpret_cast<unsigned short*>(&h);
}
__device__ __forceinline__ unsigned short rbf(float f){       // round-half-up
  return (unsigned short)((__float_as_uint(f) + 0x8000u) >> 16);
}
// XOR-swizzled LDS short-index; strideShorts*2 must be a multiple of 128B
__device__ __forceinline__ int swzi(int row, int col, int strideShorts){
  int byte = row*(strideShorts*2) + (col<<1);
  byte ^= (row & 7) << 4;
  return byte >> 1;
}

// ---------- K0: all prep, role-split by blockIdx.
// bid < 965     : bf16 tables (a1hi2, a1lo2, wg3, bsum3), g inlined on row 208
// 965..1988     : Sbf repack (8 p per block)
// bid == 1989   : kconst = sum_e bf2[e]*Wout[e] + bout
// a1hi2[224][320]: e<200,k<300 -> Att1[300+k][e]; e==208,k<300 -> g[k]; else 0
// a1lo2[224][320]: e<200: k<300 -> Att1[k][e], k==300 -> ba1[e];
//                  e==208,k<300 -> g[300+k]; else 0   (g[d] = fuse2[d]·Wout)
__global__ __launch_bounds__(256) void k_prep(
    const float* __restrict__ Att1, const float* __restrict__ ba1,
    const float* __restrict__ Wih, const float* __restrict__ bih,
    const float* __restrict__ bhh, const float* __restrict__ fuse2,
    const float* __restrict__ bf2, const float* __restrict__ Wout,
    const float* __restrict__ bout, const float* __restrict__ li,
    unsigned short* __restrict__ a1hi2, unsigned short* __restrict__ a1lo2,
    unsigned short* __restrict__ wg3, float* __restrict__ bsum3,
    unsigned short* __restrict__ Sbf, float* __restrict__ kconst)
{
  int bid = blockIdx.x, tid = threadIdx.x;
  if (bid == 1989){
    __shared__ float red[256];
    red[tid] = (tid < 200) ? bf2[tid]*Wout[tid] : 0.f;
    __syncthreads();
    for (int s=128; s>0; s>>=1){
      if (tid < s) red[tid] += red[tid+s];
      __syncthreads();
    }
    if (tid == 0) kconst[0] = red[0] + bout[0];
    return;
  }
  if (bid >= 965){                      // Sbf repack
    int pb0 = (bid - 965) * 8;
    __shared__ float s_li[8*240];
    for (int i = tid; i < 8*240; i += 256)
      s_li[i] = li[(size_t)pb0*240 + i];
    __syncthreads();
    for (int i = tid; i < 8*96; i += 256){
      int pp = i / 96, rem = i - pp*96;
      int c = rem >> 3, f = rem & 7;
      Sbf[((size_t)c*NP + pb0 + pp)*8 + f] = f2bf(s_li[pp*240 + f*12 + c]);
    }
    return;
  }
  // table region: stage Wout for the g-dot rows (cheap for all blocks)
  __shared__ float s_wout[200];
  for (int i = tid; i < 200; i += 256) s_wout[i] = Wout[i];
  __syncthreads();
  int id = bid*256 + tid;
  if (id < 71680){
    int e = id/320, k = id - e*320;
    float v = 0.f;
    if (e < 200 && k < 300){
      v = Att1[(size_t)(300+k)*200 + e];
    } else if (e == 208 && k < 300){
      const float4* fr4 = (const float4*)(fuse2 + (size_t)k*200);
      float a0=0.f,a1=0.f,a2=0.f,a3=0.f;
      #pragma unroll 5
      for (int q=0; q<50; q++){
        float4 f = fr4[q];
        float4 w = *(const float4*)&s_wout[q*4];
        a0 += f.x*w.x; a1 += f.y*w.y; a2 += f.z*w.z; a3 += f.w*w.w;
      }
      v = (a0+a1)+(a2+a3);
    }
    a1hi2[id] = f2bf(v);
  } else if (id < 143360){
    int j = id - 71680;
    int e = j/320, k = j - e*320;
    float v = 0.f;
    if (e < 200){
      if (k < 300)       v = Att1[(size_t)k*200 + e];
      else if (k == 300) v = ba1[e];
    } else if (e == 208 && k < 300){
      const float4* fr4 = (const float4*)(fuse2 + (size_t)(300+k)*200);
      float a0=0.f,a1=0.f,a2=0.f,a3=0.f;
      #pragma unroll 5
      for (int q=0; q<50; q++){
        float4 f = fr4[q];
        float4 w = *(const float4*)&s_wout[q*4];
        a0 += f.x*w.x; a1 += f.y*w.y; a2 += f.z*w.z; a3 += f.w*w.w;
      }
      v = (a0+a1)+(a2+a3);
    }
    a1lo2[j] = f2bf(v);
  } else if (id < 235520){
    int idx = id - 143360;
    int c = idx / 7680, rem = idx - c*7680;
    int np = rem >> 3, f = rem & 7;
    int G = np / 320, j = np - G*320;
    int off = (G==0) ? 0 : (G==1) ? 600 : 900;
    float v = (j<300) ? Wih[(size_t)c*9600 + (size_t)(off+j)*8 + f] : 0.f;
    wg3[idx] = f2bf(v);
  } else {
    int idx = id - 235520;   // < 11520
    int c = idx / 960, np = idx - c*960;
    int G = np / 320, j = np - G*320;
    int off = (G==0) ? 0 : (G==1) ? 600 : 900;
    bsum3[idx] = (j<300) ? (bih[c*1200+off+j] + bhh[c*1200+off+j]) : 0.f;
  }
}

// ---------- K1: fused htarget-gen (LDS) + ta/T MFMA GEMM. 32 p per block.
#define PB 32
__global__ __launch_bounds__(320) void k_ht(
    const float* __restrict__ extras, const float* __restrict__ Wt,
    const float* __restrict__ bti, const float* __restrict__ bth,
    const unsigned short* __restrict__ a1lo2,
    float* __restrict__ ta, float* __restrict__ Tbuf)
{
  int p0 = blockIdx.x * PB;
  int tid = threadIdx.x;
  __shared__ __align__(16) unsigned short s_ht[PB*KPAD];   // 20480 B
  __shared__ float s_e[PB][5];
  if (tid < PB*5) s_e[tid/5][tid%5] = extras[(size_t)(p0 + tid/5)*17 + (tid%5)];
  __syncthreads();

  int j = tid;
  if (j < 300){
    float w[15];
    #pragma unroll
    for (int f=0; f<5; f++){
      w[f]    = Wt[(size_t)j*5 + f];
      w[5+f]  = Wt[(size_t)(j+600)*5 + f];
      w[10+f] = Wt[(size_t)(j+900)*5 + f];
    }
    float bi = bti[j]     + bth[j];
    float bg = bti[j+600] + bth[j+600];
    float bo = bti[j+900] + bth[j+900];
    for (int pp=0; pp<PB; pp++){
      float gi=bi, gg=bg, go=bo;
      #pragma unroll
      for (int f=0; f<5; f++){
        float t = s_e[pp][f];
        gi += t*w[f]; gg += t*w[5+f]; go += t*w[10+f];
      }
      float cc = fsig(gi)*ftanh(gg);
      s_ht[swzi(pp, j, KPAD)] = rbf(fsig(go)*ftanh(cc));
    }
  } else {
    unsigned short v = (j == 300) ? (unsigned short)0x3F80 : (unsigned short)0;
    for (int pp=0; pp<PB; pp++)
      s_ht[swzi(pp, j, KPAD)] = v;
  }
  __syncthreads();

  // GEMM: [32 x 320] x [320 x 224]; wave w owns nt in {w, w+5, w+10} (nt<14)
  int wave = tid >> 6, lane = tid & 63;
  int lr = lane & 15, lg = lane >> 4;
  f32x4 acc[2][3];
  #pragma unroll
  for (int mt=0; mt<2; mt++)
    #pragma unroll
    for (int t=0; t<3; t++) acc[mt][t] = (f32x4){0.f,0.f,0.f,0.f};
  for (int k0=0; k0<KPAD; k0+=32){
    short8 a[2];
    #pragma unroll
    for (int mt=0; mt<2; mt++)
      a[mt] = *(const short8*)&s_ht[swzi(mt*16 + lr, lg*8 + k0, KPAD)];
    #pragma unroll
    for (int t=0; t<3; t++){
      int nt = wave + t*5;
      if (nt < NTI2){
        short8 b = *(const short8*)(a1lo2 + (size_t)(nt*16 + lr)*KPAD + lg*8 + k0);
        #pragma unroll
        for (int mt=0; mt<2; mt++)
          acc[mt][t] = __builtin_amdgcn_mfma_f32_16x16x32_bf16(a[mt], b, acc[mt][t], 0, 0, 0);
      }
    }
  }
  #pragma unroll
  for (int t=0; t<3; t++){
    int nt = wave + t*5;
    if (nt < 13){
      int e = nt*16 + lr;
      if (e < 200){
        #pragma unroll
        for (int mt=0; mt<2; mt++)
          #pragma unroll
          for (int i=0; i<4; i++)
            ta[(size_t)(p0 + mt*16 + lg*4 + i)*200 + e] = acc[mt][t][i];
      }
    } else if (nt == 13 && lr == 0){
      #pragma unroll
      for (int mt=0; mt<2; mt++)
        #pragma unroll
        for (int i=0; i<4; i++)
          Tbuf[p0 + mt*16 + lg*4 + i] = acc[mt][t][i];
    }
  }
}

// ---------- K2: gate MFMA -> h in LDS -> score GEMM (+H column)
// block: c = bid>>8, 32 consecutive p.  LDS 20480 B -> up to 8 blocks/CU.
// phase 1: wave w handles rowgroup (w&1), ch decade (w>>1).
#define PB2 32
__global__ __launch_bounds__(256) void k_hs(
    const float* __restrict__ li, const unsigned short* __restrict__ Sbf,
    const unsigned short* __restrict__ wg3, const float* __restrict__ bsum3,
    const unsigned short* __restrict__ a1hi2, const float* __restrict__ ta,
    const float* __restrict__ att2, const float* __restrict__ ba2,
    float* __restrict__ Hbuf, float* __restrict__ score)
{
  int c  = blockIdx.x >> 8;
  int p0 = (blockIdx.x & 255) << 5;
  int tid = threadIdx.x;
  int wave = tid >> 6, lane = tid & 63;
  int lr = lane & 15, lg = lane >> 4;
  __shared__ __align__(16) unsigned short s_h[PB2*KPAD];  // 20480 B

  short8 z8 = (short8){0,0,0,0,0,0,0,0};
  int rg  = wave & 1;          // rowgroup (16 p-rows)
  int chb = (wave >> 1) * 10;  // ch decade
  short8 afrag = z8;
  if (lg == 0)
    afrag = *(const short8*)(Sbf + ((size_t)c*NP + p0 + rg*16 + lr)*8);

  const unsigned short* wgc = wg3 + (size_t)c*960*8;
  const float* bsc = bsum3 + (size_t)c*960;
  f32x4 zero4 = (f32x4){0.f,0.f,0.f,0.f};
  int rowb = rg*16 + lg*4;
  for (int ch = 0; ch < 10; ch++){
    int n0 = (chb + ch)*16;
    short8 cb0 = z8, cb1 = z8, cb2 = z8;
    if (lg == 0){
      cb0 = *(const short8*)&wgc[(size_t)(      n0 + lr)*8];
      cb1 = *(const short8*)&wgc[(size_t)(320 + n0 + lr)*8];
      cb2 = *(const short8*)&wgc[(size_t)(640 + n0 + lr)*8];
    }
    f32x4 gi4 = __builtin_amdgcn_mfma_f32_16x16x32_bf16(afrag, cb0, zero4, 0, 0, 0);
    f32x4 gg4 = __builtin_amdgcn_mfma_f32_16x16x32_bf16(afrag, cb1, zero4, 0, 0, 0);
    f32x4 go4 = __builtin_amdgcn_mfma_f32_16x16x32_bf16(afrag, cb2, zero4, 0, 0, 0);
    float bi = bsc[      n0 + lr];
    float bg = bsc[320 + n0 + lr];
    float bo = bsc[640 + n0 + lr];
    #pragma unroll
    for (int i2=0; i2<4; i2++){
      float gi = gi4[i2] + bi;
      float gg = gg4[i2] + bg;
      float go = go4[i2] + bo;
      float cc = fsig(gi)*ftanh(gg);
      float hv = fsig(go)*ftanh(cc);
      s_h[swzi(rowb + i2, n0 + lr, KPAD)] = rbf(hv);
    }
  }
  __syncthreads();

  // phase 2: n-split K=320 GEMM; wave w owns nt = w + 4*t4 (<14); 2 m-tiles
  f32x4 acc[2][4];
  #pragma unroll
  for (int mt=0; mt<2; mt++)
    #pragma unroll
    for (int t4=0; t4<4; t4++) acc[mt][t4] = zero4;
  for (int k0=0; k0<KPAD; k0+=32){
    short8 a[2];
    #pragma unroll
    for (int mt=0; mt<2; mt++)
      a[mt] = *(const short8*)&s_h[swzi(mt*16 + lr, lg*8 + k0, KPAD)];
    #pragma unroll
    for (int t4=0; t4<4; t4++){
      int nt = wave + t4*4;
      if (nt < NTI2){
        short8 b = *(const short8*)(a1hi2 + (size_t)(nt*16 + lr)*KPAD + lg*8 + k0);
        #pragma unroll
        for (int mt=0; mt<2; mt++)
          acc[mt][t4] = __builtin_amdgcn_mfma_f32_16x16x32_bf16(a[mt], b, acc[mt][t4], 0, 0, 0);
      }
    }
  }

  // epilogue: score partials (ta includes ba1) + H writes (nt==13, e=208)
  float sacc[2][4];
  #pragma unroll
  for (int mt=0; mt<2; mt++)
    #pragma unroll
    for (int i=0; i<4; i++) sacc[mt][i] = 0.f;
  #pragma unroll
  for (int t4=0; t4<4; t4++){
    int nt = wave + t4*4;
    if (nt < 13){
      int e = nt*16 + lr;
      if (e < 200){
        float a2v = att2[e];
        #pragma unroll
        for (int mt=0; mt<2; mt++){
          #pragma unroll
          for (int i=0; i<4; i++){
            int p = p0 + mt*16 + lg*4 + i;
            float v = acc[mt][t4][i] + ta[(size_t)p*200 + e];
            sacc[mt][i] += fmaxf(v, 0.f) * a2v;
          }
        }
      }
    } else if (nt == 13 && lr == 0){
      #pragma unroll
      for (int mt=0; mt<2; mt++)
        #pragma unroll
        for (int i=0; i<4; i++)
          Hbuf[(size_t)(p0 + mt*16 + lg*4 + i)*NCH + c] = acc[mt][t4][i];
    }
  }
  __syncthreads();                       // s_h reads done; safe to alias
  float* s_red = reinterpret_cast<float*>(s_h);   // [4][32]
  #pragma unroll
  for (int mt=0; mt<2; mt++){
    #pragma unroll
    for (int i=0; i<4; i++){
      float s = sacc[mt][i];
      s += __shfl_xor(s, 1);
      s += __shfl_xor(s, 2);
      s += __shfl_xor(s, 4);
      s += __shfl_xor(s, 8);
      if (lr == 0) s_red[wave*32 + mt*16 + lg*4 + i] = s;
    }
  }
  __syncthreads();
  if (tid < 32){
    float r = s_red[tid] + s_red[32+tid] + s_red[64+tid] + s_red[96+tid];
    int p = p0 + tid;
    float w200 = att2[200], w201 = att2[201], b2 = ba2[0];
    float w0 = li[(size_t)p*240 + 84 + c];   // local_inputs[p,7,c]
    float w1 = li[(size_t)p*240 + 72 + c];   // local_inputs[p,6,c]
    score[(size_t)p*NCH + c] = fmaxf(r + w0*w200 + w1*w201 + b2, 0.f);
  }
}

// ---------- K3: fused softmax + output. block = t (64), thread = b (128)
__global__ __launch_bounds__(128) void k_sm_final(
    const float* __restrict__ score, const float* __restrict__ Hbuf,
    const float* __restrict__ Tbuf, const float* __restrict__ kconst,
    const float* __restrict__ labels, float* __restrict__ out)
{
  int t = blockIdx.x;
  int b = threadIdx.x;
  __shared__ float ws_f[NCH*NB];    // within-t wsoft, flat [c*128 + b]
  int p = b*NTT + t;
  const float* s = score + (size_t)p*NCH;
  float v[NCH];
  float m = -1e30f;
  #pragma unroll
  for (int c=0; c<NCH; c++){ v[c] = s[c]; m = fmaxf(m, v[c]); }
  float sum = 0.f;
  #pragma unroll
  for (int c=0; c<NCH; c++){ v[c] = __expf(v[c]-m); sum += v[c]; }
  float inv = __builtin_amdgcn_rcpf(sum);
  #pragma unroll
  for (int c=0; c<NCH; c++)
    ws_f[c*NB + b] = v[c]*inv;
  __syncthreads();
  // reference reshape scramble: w[p, c] = ws_f[b*12 + c]
  float acc = Tbuf[p] + kconst[0];
  const float* Hp = Hbuf + (size_t)p*NCH;
  int base = b*NCH;
  #pragma unroll
  for (int c=0; c<NCH; c++)
    acc += ws_f[base + c] * Hp[c];
  out[(size_t)t*NB + b] = acc;
  out[NP + (size_t)t*NB + b] = labels[p];
}

extern "C" void kernel_launch(void* const* d_in, const int* in_sizes, int n_in,
                              void* d_out, int out_size, void* d_ws, size_t ws_size,
                              hipStream_t stream)
{
  const float* li     = (const float*)d_in[0];
  const float* labels = (const float*)d_in[1];
  const float* extras = (const float*)d_in[2];
  const float* Wih    = (const float*)d_in[5];
  const float* bih    = (const float*)d_in[6];
  const float* bhh    = (const float*)d_in[7];
  const float* Wt     = (const float*)d_in[8];
  const float* bti    = (const float*)d_in[9];
  const float* bth    = (const float*)d_in[10];
  const float* Att1   = (const float*)d_in[11];
  const float* ba1    = (const float*)d_in[12];
  const float* Att2   = (const float*)d_in[13];
  const float* ba2    = (const float*)d_in[14];
  const float* fuse2  = (const float*)d_in[15];
  const float* bf2    = (const float*)d_in[16];
  const float* Wout   = (const float*)d_in[17];
  const float* bout   = (const float*)d_in[18];
  float* out = (float*)d_out;

  char* ws = (char*)d_ws;
  float* ta     = (float*)ws;                                       //  6,553,600
  float* score  = (float*)(ws + 6553600);                           //    393,216
  float* Hbuf   = (float*)(ws + 6946816);                           //    393,216
  float* Tbuf   = (float*)(ws + 7340032);                           //     32,768
  unsigned short* a1hi2 = (unsigned short*)(ws + 7372800);          //    143,360
  unsigned short* a1lo2 = (unsigned short*)(ws + 7516160);          //    143,360
  unsigned short* wg3   = (unsigned short*)(ws + 7659520);          //    184,320
  float* bsum3  = (float*)(ws + 7843840);                           //     46,080
  unsigned short* Sbf   = (unsigned short*)(ws + 7889920);          //  1,572,864
  float* kconst = (float*)(ws + 9462784);                           //          4

  k_prep<<<1990, 256, 0, stream>>>(Att1, ba1, Wih, bih, bhh, fuse2, bf2,
                                   Wout, bout, li,
                                   a1hi2, a1lo2, wg3, bsum3, Sbf, kconst);
  k_ht<<<NP/PB, 320, 0, stream>>>(extras, Wt, bti, bth, a1lo2, ta, Tbuf);
  k_hs<<<NCH*256, 256, 0, stream>>>(li, Sbf, wg3, bsum3, a1hi2, ta, Att2, ba2,
                                    Hbuf, score);
  k_sm_final<<<NTT, NB, 0, stream>>>(score, Hbuf, Tbuf, kconst, labels, out);
}

// Round 12
// 172.826 us; speedup vs baseline: 1.1507x; 1.1507x over previous
//
#include <hip/hip_runtime.h>
#include <hip/hip_bf16.h>

#define HH   300
#define NB   128
#define NTT  64
#define NP   8192        // B*T
#define NCH  12
#define KPAD 320         // padded K (300 -> 320)
#define NTI2 14          // 13 e-tiles + 1 g-tile (H / T column at e=208)
#define L2E  1.442695041f
#define L2E2 2.885390082f

typedef __attribute__((ext_vector_type(8))) short short8;
typedef __attribute__((ext_vector_type(4))) float f32x4;

__device__ __forceinline__ float fsig(float x){
  return __builtin_amdgcn_rcpf(1.f + __expf(-x));
}
__device__ __forceinline__ float ftanh(float x){
  float e = __expf(2.f*x);
  return 1.f - 2.f*__builtin_amdgcn_rcpf(e + 1.f);   // safe at +/-inf
}
// prescaled variants: input already multiplied by log2e (sig) / 2log2e (tanh)
__device__ __forceinline__ float fsig2(float xs){   // xs = x*log2e
  return __builtin_amdgcn_rcpf(1.f + __builtin_amdgcn_exp2f(-xs));
}
__device__ __forceinline__ float ftanh2(float xs){  // xs = 2x*log2e
  return 1.f - 2.f*__builtin_amdgcn_rcpf(__builtin_amdgcn_exp2f(xs) + 1.f);
}
__device__ __forceinline__ float bf2f(unsigned short u){
  return __uint_as_float(((unsigned)u) << 16);
}
__device__ __forceinline__ unsigned short f2bf(float f){      // RNE
  __hip_bfloat16 h = __float2bfloat16(f);
  return *reinterpret_cast<unsigned short*>(&h);
}
__device__ __forceinline__ unsigned short rbf(float f){       // round-half-up
  return (unsigned short)((__float_as_uint(f) + 0x8000u) >> 16);
}
// XOR-swizzled LDS short-index; strideShorts*2 must be a multiple of 128B
__device__ __forceinline__ int swzi(int row, int col, int strideShorts){
  int byte = row*(strideShorts*2) + (col<<1);
  byte ^= (row & 7) << 4;
  return byte >> 1;
}

// ---------- K0: all prep, role-split by blockIdx.
// bid < 965     : bf16 tables (a1hi2, a1lo2, wg3, bsum3), g inlined on row 208
// 965..1988     : Sbf repack (8 p per block)
// bid == 1989   : kconst = sum_e bf2[e]*Wout[e] + bout
// wg3/bsum3 are PRESCALED: i,o gates x log2e; g gate x 2log2e (exp2 tail).
__global__ __launch_bounds__(256) void k_prep(
    const float* __restrict__ Att1, const float* __restrict__ ba1,
    const float* __restrict__ Wih, const float* __restrict__ bih,
    const float* __restrict__ bhh, const float* __restrict__ fuse2,
    const float* __restrict__ bf2, const float* __restrict__ Wout,
    const float* __restrict__ bout, const float* __restrict__ li,
    unsigned short* __restrict__ a1hi2, unsigned short* __restrict__ a1lo2,
    unsigned short* __restrict__ wg3, float* __restrict__ bsum3,
    unsigned short* __restrict__ Sbf, float* __restrict__ kconst)
{
  int bid = blockIdx.x, tid = threadIdx.x;
  if (bid == 1989){
    __shared__ float red[256];
    red[tid] = (tid < 200) ? bf2[tid]*Wout[tid] : 0.f;
    __syncthreads();
    for (int s=128; s>0; s>>=1){
      if (tid < s) red[tid] += red[tid+s];
      __syncthreads();
    }
    if (tid == 0) kconst[0] = red[0] + bout[0];
    return;
  }
  if (bid >= 965){                      // Sbf repack
    int pb0 = (bid - 965) * 8;
    __shared__ float s_li[8*240];
    for (int i = tid; i < 8*240; i += 256)
      s_li[i] = li[(size_t)pb0*240 + i];
    __syncthreads();
    for (int i = tid; i < 8*96; i += 256){
      int pp = i / 96, rem = i - pp*96;
      int c = rem >> 3, f = rem & 7;
      Sbf[((size_t)c*NP + pb0 + pp)*8 + f] = f2bf(s_li[pp*240 + f*12 + c]);
    }
    return;
  }
  __shared__ float s_wout[200];
  for (int i = tid; i < 200; i += 256) s_wout[i] = Wout[i];
  __syncthreads();
  int id = bid*256 + tid;
  if (id < 71680){
    int e = id/320, k = id - e*320;
    float v = 0.f;
    if (e < 200 && k < 300){
      v = Att1[(size_t)(300+k)*200 + e];
    } else if (e == 208 && k < 300){
      const float4* fr4 = (const float4*)(fuse2 + (size_t)k*200);
      float a0=0.f,a1=0.f,a2=0.f,a3=0.f;
      #pragma unroll 5
      for (int q=0; q<50; q++){
        float4 f = fr4[q];
        float4 w = *(const float4*)&s_wout[q*4];
        a0 += f.x*w.x; a1 += f.y*w.y; a2 += f.z*w.z; a3 += f.w*w.w;
      }
      v = (a0+a1)+(a2+a3);
    }
    a1hi2[id] = f2bf(v);
  } else if (id < 143360){
    int j = id - 71680;
    int e = j/320, k = j - e*320;
    float v = 0.f;
    if (e < 200){
      if (k < 300)       v = Att1[(size_t)k*200 + e];
      else if (k == 300) v = ba1[e];
    } else if (e == 208 && k < 300){
      const float4* fr4 = (const float4*)(fuse2 + (size_t)(300+k)*200);
      float a0=0.f,a1=0.f,a2=0.f,a3=0.f;
      #pragma unroll 5
      for (int q=0; q<50; q++){
        float4 f = fr4[q];
        float4 w = *(const float4*)&s_wout[q*4];
        a0 += f.x*w.x; a1 += f.y*w.y; a2 += f.z*w.z; a3 += f.w*w.w;
      }
      v = (a0+a1)+(a2+a3);
    }
    a1lo2[j] = f2bf(v);
  } else if (id < 235520){
    int idx = id - 143360;
    int c = idx / 7680, rem = idx - c*7680;
    int np = rem >> 3, f = rem & 7;
    int G = np / 320, j = np - G*320;
    int off = (G==0) ? 0 : (G==1) ? 600 : 900;
    float sc  = (G==1) ? L2E2 : L2E;
    float v = (j<300) ? Wih[(size_t)c*9600 + (size_t)(off+j)*8 + f] * sc : 0.f;
    wg3[idx] = f2bf(v);
  } else {
    int idx = id - 235520;   // < 11520
    int c = idx / 960, np = idx - c*960;
    int G = np / 320, j = np - G*320;
    int off = (G==0) ? 0 : (G==1) ? 600 : 900;
    float sc  = (G==1) ? L2E2 : L2E;
    bsum3[idx] = (j<300) ? (bih[c*1200+off+j] + bhh[c*1200+off+j]) * sc : 0.f;
  }
}

// ---------- K1: fused htarget-gen (LDS) + ta/T MFMA GEMM. 16 p per block.
#define PB 16
__global__ __launch_bounds__(320) void k_ht(
    const float* __restrict__ extras, const float* __restrict__ Wt,
    const float* __restrict__ bti, const float* __restrict__ bth,
    const unsigned short* __restrict__ a1lo2,
    float* __restrict__ ta, float* __restrict__ Tbuf)
{
  int p0 = blockIdx.x * PB;
  int tid = threadIdx.x;
  __shared__ __align__(16) unsigned short s_ht[PB*KPAD];   // 10240 B
  __shared__ float s_e[PB][5];
  if (tid < PB*5) s_e[tid/5][tid%5] = extras[(size_t)(p0 + tid/5)*17 + (tid%5)];
  __syncthreads();

  int j = tid;
  if (j < 300){
    float w[15];
    #pragma unroll
    for (int f=0; f<5; f++){
      w[f]    = Wt[(size_t)j*5 + f];
      w[5+f]  = Wt[(size_t)(j+600)*5 + f];
      w[10+f] = Wt[(size_t)(j+900)*5 + f];
    }
    float bi = bti[j]     + bth[j];
    float bg = bti[j+600] + bth[j+600];
    float bo = bti[j+900] + bth[j+900];
    for (int pp=0; pp<PB; pp++){
      float gi=bi, gg=bg, go=bo;
      #pragma unroll
      for (int f=0; f<5; f++){
        float t = s_e[pp][f];
        gi += t*w[f]; gg += t*w[5+f]; go += t*w[10+f];
      }
      float cc = fsig(gi)*ftanh(gg);
      s_ht[swzi(pp, j, KPAD)] = rbf(fsig(go)*ftanh(cc));
    }
  } else {
    unsigned short v = (j == 300) ? (unsigned short)0x3F80 : (unsigned short)0;
    for (int pp=0; pp<PB; pp++)
      s_ht[swzi(pp, j, KPAD)] = v;
  }
  __syncthreads();

  // GEMM: [16 x 320] x [320 x 224]; wave w owns nt in {w, w+5, w+10} (nt<14)
  int wave = tid >> 6, lane = tid & 63;
  int lr = lane & 15, lg = lane >> 4;
  f32x4 acc[3];
  #pragma unroll
  for (int t=0; t<3; t++) acc[t] = (f32x4){0.f,0.f,0.f,0.f};
  for (int k0=0; k0<KPAD; k0+=32){
    short8 a = *(const short8*)&s_ht[swzi(lr, lg*8 + k0, KPAD)];
    #pragma unroll
    for (int t=0; t<3; t++){
      int nt = wave + t*5;
      if (nt < NTI2){
        short8 b = *(const short8*)(a1lo2 + (size_t)(nt*16 + lr)*KPAD + lg*8 + k0);
        acc[t] = __builtin_amdgcn_mfma_f32_16x16x32_bf16(a, b, acc[t], 0, 0, 0);
      }
    }
  }
  #pragma unroll
  for (int t=0; t<3; t++){
    int nt = wave + t*5;
    if (nt < 13){
      int e = nt*16 + lr;
      if (e < 200){
        #pragma unroll
        for (int i=0; i<4; i++)
          ta[(size_t)(p0 + lg*4 + i)*200 + e] = acc[t][i];
      }
    } else if (nt == 13 && lr == 0){
      #pragma unroll
      for (int i=0; i<4; i++)
        Tbuf[p0 + lg*4 + i] = acc[t][i];
    }
  }
}

// ---------- K2: gate MFMA -> h in LDS -> score GEMM (+H column). 8 waves/tile.
// block: c = bid>>7, 64 consecutive p. LDS 40960 B, 512 threads.
// phase 1: wave w -> m-tile (w&3), ch-half (w>>2)*10. phase 2: nt = w, w+8.
__global__ __launch_bounds__(512, 6) void k_hs(
    const float* __restrict__ li, const unsigned short* __restrict__ Sbf,
    const unsigned short* __restrict__ wg3, const float* __restrict__ bsum3,
    const unsigned short* __restrict__ a1hi2, const float* __restrict__ ta,
    const float* __restrict__ att2, const float* __restrict__ ba2,
    float* __restrict__ Hbuf, float* __restrict__ score)
{
  int c  = blockIdx.x >> 7;
  int p0 = (blockIdx.x & 127) << 6;
  int tid = threadIdx.x;
  int wave = tid >> 6, lane = tid & 63;
  int lr = lane & 15, lg = lane >> 4;
  __shared__ __align__(16) unsigned short s_h[64*KPAD];  // 40960 B

  short8 z8 = (short8){0,0,0,0,0,0,0,0};
  int mt1 = wave & 3;          // phase-1 m-tile (16 p-rows)
  int chb = (wave >> 2) * 10;  // phase-1 ch half
  short8 afrag = z8;
  if (lg == 0)
    afrag = *(const short8*)(Sbf + ((size_t)c*NP + p0 + mt1*16 + lr)*8);

  const unsigned short* wgc = wg3 + (size_t)c*960*8;
  const float* bsc = bsum3 + (size_t)c*960;
  f32x4 zero4 = (f32x4){0.f,0.f,0.f,0.f};
  int rowb = mt1*16 + lg*4;
  short8 nb0 = z8, nb1 = z8, nb2 = z8;
  if (lg == 0){
    int nr = chb*16 + lr;
    nb0 = *(const short8*)&wgc[(size_t)(      nr)*8];
    nb1 = *(const short8*)&wgc[(size_t)(320 + nr)*8];
    nb2 = *(const short8*)&wgc[(size_t)(640 + nr)*8];
  }
  for (int ch = 0; ch < 10; ch++){
    int n0 = (chb + ch)*16;
    short8 cb0 = nb0, cb1 = nb1, cb2 = nb2;
    if (ch < 9 && lg == 0){
      int nn = n0 + 16 + lr;
      nb0 = *(const short8*)&wgc[(size_t)(      nn)*8];
      nb1 = *(const short8*)&wgc[(size_t)(320 + nn)*8];
      nb2 = *(const short8*)&wgc[(size_t)(640 + nn)*8];
    }
    f32x4 gi4 = __builtin_amdgcn_mfma_f32_16x16x32_bf16(afrag, cb0, zero4, 0, 0, 0);
    f32x4 gg4 = __builtin_amdgcn_mfma_f32_16x16x32_bf16(afrag, cb1, zero4, 0, 0, 0);
    f32x4 go4 = __builtin_amdgcn_mfma_f32_16x16x32_bf16(afrag, cb2, zero4, 0, 0, 0);
    float bi = bsc[      n0 + lr];
    float bg = bsc[320 + n0 + lr];
    float bo = bsc[640 + n0 + lr];
    #pragma unroll
    for (int i2=0; i2<4; i2++){
      float si = fsig2(gi4[i2] + bi);        // inputs prescaled by log2e
      float tg = ftanh2(gg4[i2] + bg);       // prescaled by 2log2e
      float cc = si*tg;
      float tc = ftanh2(cc * L2E2);
      float so = fsig2(go4[i2] + bo);
      s_h[swzi(rowb + i2, n0 + lr, KPAD)] = rbf(so*tc);
    }
  }
  __syncthreads();

  // phase 2: nt = wave + 8*t (t<2); all 4 m-tiles per wave
  f32x4 acc[4][2];
  #pragma unroll
  for (int mt=0; mt<4; mt++)
    #pragma unroll
    for (int t=0; t<2; t++) acc[mt][t] = zero4;
  for (int k0=0; k0<KPAD; k0+=32){
    short8 a[4];
    #pragma unroll
    for (int mt=0; mt<4; mt++)
      a[mt] = *(const short8*)&s_h[swzi(mt*16 + lr, lg*8 + k0, KPAD)];
    #pragma unroll
    for (int t=0; t<2; t++){
      int nt = wave + t*8;
      if (nt < NTI2){
        short8 b = *(const short8*)(a1hi2 + (size_t)(nt*16 + lr)*KPAD + lg*8 + k0);
        #pragma unroll
        for (int mt=0; mt<4; mt++)
          acc[mt][t] = __builtin_amdgcn_mfma_f32_16x16x32_bf16(a[mt], b, acc[mt][t], 0, 0, 0);
      }
    }
  }

  // epilogue: score partials (ta includes ba1) + H writes (nt==13 -> wave 5)
  float sacc[4][4];
  #pragma unroll
  for (int mt=0; mt<4; mt++)
    #pragma unroll
    for (int i=0; i<4; i++) sacc[mt][i] = 0.f;
  #pragma unroll
  for (int t=0; t<2; t++){
    int nt = wave + t*8;
    if (nt < 13){
      int e = nt*16 + lr;
      if (e < 200){
        float a2v = att2[e];
        #pragma unroll
        for (int mt=0; mt<4; mt++){
          #pragma unroll
          for (int i=0; i<4; i++){
            int p = p0 + mt*16 + lg*4 + i;
            float v = acc[mt][t][i] + ta[(size_t)p*200 + e];
            sacc[mt][i] += fmaxf(v, 0.f) * a2v;
          }
        }
      }
    } else if (nt == 13 && lr == 0){
      #pragma unroll
      for (int mt=0; mt<4; mt++)
        #pragma unroll
        for (int i=0; i<4; i++)
          Hbuf[(size_t)(p0 + mt*16 + lg*4 + i)*NCH + c] = acc[mt][t][i];
    }
  }
  __syncthreads();                       // s_h reads done; safe to alias
  float* s_red = reinterpret_cast<float*>(s_h);   // [8][64]
  #pragma unroll
  for (int mt=0; mt<4; mt++){
    #pragma unroll
    for (int i=0; i<4; i++){
      float s = sacc[mt][i];
      s += __shfl_xor(s, 1);
      s += __shfl_xor(s, 2);
      s += __shfl_xor(s, 4);
      s += __shfl_xor(s, 8);
      if (lr == 0) s_red[wave*64 + mt*16 + lg*4 + i] = s;
    }
  }
  __syncthreads();
  if (tid < 64){
    float r = 0.f;
    #pragma unroll
    for (int w8=0; w8<8; w8++) r += s_red[w8*64 + tid];
    int p = p0 + tid;
    float w200 = att2[200], w201 = att2[201], b2 = ba2[0];
    float w0 = li[(size_t)p*240 + 84 + c];   // local_inputs[p,7,c]
    float w1 = li[(size_t)p*240 + 72 + c];   // local_inputs[p,6,c]
    score[(size_t)p*NCH + c] = fmaxf(r + w0*w200 + w1*w201 + b2, 0.f);
  }
}

// ---------- K3: fused softmax + output. block = t (64), thread = b (128)
__global__ __launch_bounds__(128) void k_sm_final(
    const float* __restrict__ score, const float* __restrict__ Hbuf,
    const float* __restrict__ Tbuf, const float* __restrict__ kconst,
    const float* __restrict__ labels, float* __restrict__ out)
{
  int t = blockIdx.x;
  int b = threadIdx.x;
  __shared__ float ws_f[NCH*NB];    // within-t wsoft, flat [c*128 + b]
  int p = b*NTT + t;
  const float* s = score + (size_t)p*NCH;
  float v[NCH];
  float m = -1e30f;
  #pragma unroll
  for (int c=0; c<NCH; c++){ v[c] = s[c]; m = fmaxf(m, v[c]); }
  float sum = 0.f;
  #pragma unroll
  for (int c=0; c<NCH; c++){ v[c] = __expf(v[c]-m); sum += v[c]; }
  float inv = __builtin_amdgcn_rcpf(sum);
  #pragma unroll
  for (int c=0; c<NCH; c++)
    ws_f[c*NB + b] = v[c]*inv;
  __syncthreads();
  // reference reshape scramble: w[p, c] = ws_f[b*12 + c]
  float acc = Tbuf[p] + kconst[0];
  const float* Hp = Hbuf + (size_t)p*NCH;
  int base = b*NCH;
  #pragma unroll
  for (int c=0; c<NCH; c++)
    acc += ws_f[base + c] * Hp[c];
  out[(size_t)t*NB + b] = acc;
  out[NP + (size_t)t*NB + b] = labels[p];
}

extern "C" void kernel_launch(void* const* d_in, const int* in_sizes, int n_in,
                              void* d_out, int out_size, void* d_ws, size_t ws_size,
                              hipStream_t stream)
{
  const float* li     = (const float*)d_in[0];
  const float* labels = (const float*)d_in[1];
  const float* extras = (const float*)d_in[2];
  const float* Wih    = (const float*)d_in[5];
  const float* bih    = (const float*)d_in[6];
  const float* bhh    = (const float*)d_in[7];
  const float* Wt     = (const float*)d_in[8];
  const float* bti    = (const float*)d_in[9];
  const float* bth    = (const float*)d_in[10];
  const float* Att1   = (const float*)d_in[11];
  const float* ba1    = (const float*)d_in[12];
  const float* Att2   = (const float*)d_in[13];
  const float* ba2    = (const float*)d_in[14];
  const float* fuse2  = (const float*)d_in[15];
  const float* bf2    = (const float*)d_in[16];
  const float* Wout   = (const float*)d_in[17];
  const float* bout   = (const float*)d_in[18];
  float* out = (float*)d_out;

  char* ws = (char*)d_ws;
  float* ta     = (float*)ws;                                       //  6,553,600
  float* score  = (float*)(ws + 6553600);                           //    393,216
  float* Hbuf   = (float*)(ws + 6946816);                           //    393,216
  float* Tbuf   = (float*)(ws + 7340032);                           //     32,768
  unsigned short* a1hi2 = (unsigned short*)(ws + 7372800);          //    143,360
  unsigned short* a1lo2 = (unsigned short*)(ws + 7516160);          //    143,360
  unsigned short* wg3   = (unsigned short*)(ws + 7659520);          //    184,320
  float* bsum3  = (float*)(ws + 7843840);                           //     46,080
  unsigned short* Sbf   = (unsigned short*)(ws + 7889920);          //  1,572,864
  float* kconst = (float*)(ws + 9462784);                           //          4

  k_prep<<<1990, 256, 0, stream>>>(Att1, ba1, Wih, bih, bhh, fuse2, bf2,
                                   Wout, bout, li,
                                   a1hi2, a1lo2, wg3, bsum3, Sbf, kconst);
  k_ht<<<NP/PB, 320, 0, stream>>>(extras, Wt, bti, bth, a1lo2, ta, Tbuf);
  k_hs<<<NCH*128, 512, 0, stream>>>(li, Sbf, wg3, bsum3, a1hi2, ta, Att2, ba2,
                                    Hbuf, score);
  k_sm_final<<<NTT, NB, 0, stream>>>(score, Hbuf, Tbuf, kconst, labels, out);
}